// Round 9
// baseline (651.985 us; speedup 1.0000x reference)
//
#include <hip/hip_runtime.h>

typedef short bf16x8 __attribute__((ext_vector_type(8)));
typedef float f32x4 __attribute__((ext_vector_type(4)));

#define BROWS 65536
#define EPS_BN 1e-5f
#define NSTD 0.1f

// ws layout: [0, 5120)            : 5 nodes x (sum[128], sumsq[128]) fp32 stats
//            [8192, 8192+1.97MB)  : split-bf16 FRAGMENT-MAJOR tiled weights, per node:
//   W1 hi: [kt(8)][ntile(16)][lane(64)][8]  (65536 shorts), W1 lo at +65536
//   W2 hi: [kt(8)][ntile(8)][lane(64)][8]   (32768 shorts) at +131072, W2 lo at +32768 from there
// Tile semantics: n = ntile*16 + (lane&15), k = kt*32 + (lane>>4)*8 + j  -> exactly the
// MFMA B-fragment each lane needs, so a wave's load is base + lane*16B = 1KB coalesced.
#define WNODE 196608   // shorts per node
#define WOFF  8192     // byte offset of weights in ws

__device__ __forceinline__ void split1(float x, short& hi, short& lo) {
  unsigned u = __float_as_uint(x);
  hi = (short)(u >> 16);
  float hf = __uint_as_float(u & 0xffff0000u);
  float l = x - hf;
  lo = (short)(__float_as_uint(l) >> 16);
}

__global__ void zero_f32(float* p, int n) {
  int i = blockIdx.x * blockDim.x + threadIdx.x;
  if (i < n) p[i] = 0.0f;
}

// Transpose + split weights into fragment-major tiles (see header comment).
__global__ __launch_bounds__(256) void prep_weights(const float* W1, const float* W2, short* wbuf) {
  int u = blockIdx.x * 256 + threadIdx.x;   // 61440 units, 8 k-elems each
  if (u >= 61440) return;
  if (u < 40960) {                           // W1: 5 nodes x 8 kt x 16 ntile x 64 lanes
    int node = u >> 13;
    int r = u & 8191;
    int kt = r >> 10;
    int r2 = r & 1023;
    int ntile = r2 >> 6;
    int ln = r2 & 63;
    int n = ntile * 16 + (ln & 15);
    int k0 = kt * 32 + (ln >> 4) * 8;
    const float* src = W1 + (size_t)node * 65536 + (size_t)k0 * 256 + n;
    short* dsthi = wbuf + (size_t)node * WNODE + kt * 8192 + ntile * 512 + ln * 8;
    bf16x8 h8, l8;
    #pragma unroll
    for (int j = 0; j < 8; ++j) { short hh, ll; split1(src[j * 256], hh, ll); h8[j] = hh; l8[j] = ll; }
    *(bf16x8*)dsthi = h8;
    *(bf16x8*)(dsthi + 65536) = l8;
  } else {                                   // W2: 5 nodes x 8 kt x 8 ntile x 64 lanes
    int u2 = u - 40960;
    int node = u2 >> 12;
    int r = u2 & 4095;
    int kt = r >> 9;
    int r2 = r & 511;
    int ntile = r2 >> 6;
    int ln = r2 & 63;
    int n = ntile * 16 + (ln & 15);
    int k0 = kt * 32 + (ln >> 4) * 8;
    const float* src = W2 + (size_t)node * 32768 + (size_t)k0 * 128 + n;
    short* dsthi = wbuf + (size_t)node * WNODE + 131072 + kt * 4096 + ntile * 512 + ln * 8;
    bf16x8 h8, l8;
    #pragma unroll
    for (int j = 0; j < 8; ++j) { short hh, ll; split1(src[j * 128], hh, ll); h8[j] = hh; l8[j] = ll; }
    *(bf16x8*)dsthi = h8;
    *(bf16x8*)(dsthi + 32768) = l8;
  }
}

struct NodeA {
  const float* inA;   // cols 0..127, row stride ldA
  const float* inB;   // cols 128..255, row stride ldB
  int ldA, ldB;
  const short* w1t;   // tiled, hi at 0, lo at +65536 shorts
  const short* w2t;   // tiled, hi at 0, lo at +32768 shorts
  const float* b1; const float* b2;
  float* y; float* sum; float* sumsq;
};

struct NodeC {
  const float* y; float* out;
  const float* sum; const float* sumsq;
  const float* gamma; const float* beta;
  const float* noise;
};

// ---- software-pipeline macros (named register sets; all indices compile-time) ----
#define LOADB1(S, kt) do { \
  _Pragma("unroll") \
  for (int nf = 0; nf < 4; ++nf) { \
    int tb = (kt) * 8192 + (nq * 4 + nf) * 512 + lane * 8; \
    bh##S[nf] = *(const bf16x8*)(w1hi + tb); \
    bl##S[nf] = *(const bf16x8*)(w1lo + tb); \
  } } while (0)

#define COMPUTE1(S, kt) do { \
  int kb = (kt) * 32 + l4 * 8; \
  bf16x8 ahi0, alo0, ahi1, alo1; \
  { int row = mh * 32 + l15; int off = row * 512 + ((kb * 2) ^ ((row & 7) << 4)); \
    ahi0 = *(const bf16x8*)((const char*)lds[0] + off); \
    alo0 = *(const bf16x8*)((const char*)lds[1] + off); } \
  { int row = mh * 32 + 16 + l15; int off = row * 512 + ((kb * 2) ^ ((row & 7) << 4)); \
    ahi1 = *(const bf16x8*)((const char*)lds[0] + off); \
    alo1 = *(const bf16x8*)((const char*)lds[1] + off); } \
  _Pragma("unroll") \
  for (int nf = 0; nf < 4; ++nf) { \
    acc[0][nf] = __builtin_amdgcn_mfma_f32_16x16x32_bf16(ahi0, bh##S[nf], acc[0][nf], 0, 0, 0); \
    acc[0][nf] = __builtin_amdgcn_mfma_f32_16x16x32_bf16(ahi0, bl##S[nf], acc[0][nf], 0, 0, 0); \
    acc[0][nf] = __builtin_amdgcn_mfma_f32_16x16x32_bf16(alo0, bh##S[nf], acc[0][nf], 0, 0, 0); \
    acc[1][nf] = __builtin_amdgcn_mfma_f32_16x16x32_bf16(ahi1, bh##S[nf], acc[1][nf], 0, 0, 0); \
    acc[1][nf] = __builtin_amdgcn_mfma_f32_16x16x32_bf16(ahi1, bl##S[nf], acc[1][nf], 0, 0, 0); \
    acc[1][nf] = __builtin_amdgcn_mfma_f32_16x16x32_bf16(alo1, bh##S[nf], acc[1][nf], 0, 0, 0); \
  } } while (0)

#define LOADB2(S, kt) do { \
  _Pragma("unroll") \
  for (int nf = 0; nf < 2; ++nf) { \
    int tb = (kt) * 4096 + (nq * 2 + nf) * 512 + lane * 8; \
    ch##S[nf] = *(const bf16x8*)(w2hi + tb); \
    cl##S[nf] = *(const bf16x8*)(w2lo + tb); \
  } } while (0)

#define COMPUTE2(S, kt) do { \
  int kb = (kt) * 32 + l4 * 8; \
  bf16x8 ahi0, alo0, ahi1, alo1; \
  { int row = mh * 32 + l15; int off = row * 512 + ((kb * 2) ^ ((row & 7) << 4)); \
    ahi0 = *(const bf16x8*)((const char*)lds[0] + off); \
    alo0 = *(const bf16x8*)((const char*)lds[1] + off); } \
  { int row = mh * 32 + 16 + l15; int off = row * 512 + ((kb * 2) ^ ((row & 7) << 4)); \
    ahi1 = *(const bf16x8*)((const char*)lds[0] + off); \
    alo1 = *(const bf16x8*)((const char*)lds[1] + off); } \
  _Pragma("unroll") \
  for (int nf = 0; nf < 2; ++nf) { \
    acc2[0][nf] = __builtin_amdgcn_mfma_f32_16x16x32_bf16(ahi0, ch##S[nf], acc2[0][nf], 0, 0, 0); \
    acc2[0][nf] = __builtin_amdgcn_mfma_f32_16x16x32_bf16(ahi0, cl##S[nf], acc2[0][nf], 0, 0, 0); \
    acc2[0][nf] = __builtin_amdgcn_mfma_f32_16x16x32_bf16(alo0, ch##S[nf], acc2[0][nf], 0, 0, 0); \
    acc2[1][nf] = __builtin_amdgcn_mfma_f32_16x16x32_bf16(ahi1, ch##S[nf], acc2[1][nf], 0, 0, 0); \
    acc2[1][nf] = __builtin_amdgcn_mfma_f32_16x16x32_bf16(ahi1, cl##S[nf], acc2[1][nf], 0, 0, 0); \
    acc2[1][nf] = __builtin_amdgcn_mfma_f32_16x16x32_bf16(alo1, ch##S[nf], acc2[1][nf], 0, 0, 0); \
  } } while (0)

// Fused split-bf16 MFMA node: y = relu(x@W1+b1)@W2 + b2, + column sum/sumsq.
// 512 threads (8 waves), tile 64 rows. Wave grid: 2(M) x 4(N). 2-deep B prefetch.
__global__ __launch_bounds__(512) void mlp_node(NodeA nd0, NodeA nd1) {
  const NodeA nd = (blockIdx.y == 0) ? nd0 : nd1;
  __shared__ short lds[2][64 * 256];   // hi/lo planes, XOR-swizzled rows (64 KB)

  const int tid = threadIdx.x;
  const int lane = tid & 63;
  const int wid = tid >> 6;
  const int l15 = lane & 15;
  const int l4 = lane >> 4;            // 0..3
  const int m0 = blockIdx.x * 64;
  const int mh = wid >> 2;             // 0..1 : 32-row half
  const int nq = wid & 3;              // 0..3

  const short* __restrict__ w1hi = nd.w1t;
  const short* __restrict__ w1lo = nd.w1t + 65536;
  const short* __restrict__ w2hi = nd.w2t;
  const short* __restrict__ w2lo = nd.w2t + 32768;

  // hoisted bias loads
  float bb1[4], bb2[2];
  #pragma unroll
  for (int nf = 0; nf < 4; ++nf) bb1[nf] = nd.b1[nq * 64 + nf * 16 + l15];
  #pragma unroll
  for (int nf = 0; nf < 2; ++nf) bb2[nf] = nd.b2[nq * 32 + nf * 16 + l15];

  bf16x8 bh0[4], bl0[4], bh1[4], bl1[4];   // GEMM1 B double-buffer

  // ---- stage X (64x256 fp32) -> split bf16 hi/lo planes in LDS ----
  #pragma unroll
  for (int it = 0; it < 4; ++it) {
    int u = tid + it * 512;            // 2048 units of 8 elems
    int row = u >> 5, kc = u & 31;
    const float* src = (kc < 16) ? (nd.inA + (size_t)(m0 + row) * nd.ldA + kc * 8)
                                 : (nd.inB + (size_t)(m0 + row) * nd.ldB + (kc - 16) * 8);
    float4 a = *(const float4*)src;
    float4 b = *(const float4*)(src + 4);
    bf16x8 h8, l8;
    #pragma unroll
    for (int j = 0; j < 8; ++j) {
      float f = (j < 4) ? (&a.x)[j] : (&b.x)[j - 4];
      short hh, ll; split1(f, hh, ll);
      h8[j] = hh; l8[j] = ll;
    }
    int off = row * 512 + ((kc * 16) ^ ((row & 7) << 4));
    *(bf16x8*)((char*)lds[0] + off) = h8;
    *(bf16x8*)((char*)lds[1] + off) = l8;
  }
  LOADB1(0, 0);                        // prefetch kt=0 B while barrier drains
  __syncthreads();

  // ---- GEMM1: H(64x256) = X @ W1  (3-product split-bf16, 2-deep pipeline) ----
  f32x4 acc[2][4] = {};
  #pragma unroll
  for (int kt = 0; kt < 8; kt += 2) {
    LOADB1(1, kt + 1);
    COMPUTE1(0, kt);
    if (kt + 2 < 8) LOADB1(0, kt + 2);
    COMPUTE1(1, kt + 1);
  }
  bf16x8 ch0[2], cl0[2], ch1[2], cl1[2];   // GEMM2 B double-buffer
  LOADB2(0, 0);                        // prefetch GEMM2 kt=0 before repack barrier
  __syncthreads();   // all waves done reading X planes

  // ---- bias + relu + split -> H planes (overwrite X planes) ----
  #pragma unroll
  for (int nf = 0; nf < 4; ++nf) {
    int col = nq * 64 + nf * 16 + l15;
    float bb = bb1[nf];
    #pragma unroll
    for (int mf = 0; mf < 2; ++mf) {
      int rowb = mh * 32 + mf * 16 + l4 * 4;
      #pragma unroll
      for (int r = 0; r < 4; ++r) {
        float h = fmaxf(acc[mf][nf][r] + bb, 0.f);
        short hh, ll; split1(h, hh, ll);
        int off = (rowb + r) * 512 + ((col * 2) ^ (((rowb + r) & 7) << 4));
        *(short*)((char*)lds[0] + off) = hh;
        *(short*)((char*)lds[1] + off) = ll;
      }
    }
  }
  __syncthreads();

  // ---- GEMM2: Y(64x128) = H @ W2  (2-deep pipeline) ----
  f32x4 acc2[2][2] = {};
  #pragma unroll
  for (int kt = 0; kt < 8; kt += 2) {
    LOADB2(1, kt + 1);
    COMPUTE2(0, kt);
    if (kt + 2 < 8) LOADB2(0, kt + 2);
    COMPUTE2(1, kt + 1);
  }
  __syncthreads();   // done with H planes

  // ---- epilogue: +b2, store y, column sum/sumsq ----
  float* red = (float*)lds;            // 256 floats reused
  if (tid < 256) red[tid] = 0.f;
  __syncthreads();
  #pragma unroll
  for (int nf = 0; nf < 2; ++nf) {
    int col = nq * 32 + nf * 16 + l15;
    float bb = bb2[nf];
    #pragma unroll
    for (int mf = 0; mf < 2; ++mf) {
      int rowb = m0 + mh * 32 + mf * 16 + l4 * 4;
      float s = 0.f, q = 0.f;
      #pragma unroll
      for (int r = 0; r < 4; ++r) {
        float v = acc2[mf][nf][r] + bb;
        nd.y[(size_t)(rowb + r) * 128 + col] = v;
        s += v; q += v * v;
      }
      atomicAdd(&red[col], s);
      atomicAdd(&red[128 + col], q);
    }
  }
  __syncthreads();
  if (tid < 128)      atomicAdd(&nd.sum[tid], red[tid]);
  else if (tid < 256) atomicAdd(&nd.sumsq[tid - 128], red[tid]);
}

// BN normalize (in place) + optional noise. One thread = one float4 (4 cols).
__global__ __launch_bounds__(256) void bn_apply(NodeC c0, NodeC c1) {
  const NodeC c = (blockIdx.y == 0) ? c0 : c1;
  const size_t e = (size_t)blockIdx.x * blockDim.x + threadIdx.x;  // float4 idx
  const int col4 = ((int)e & 31) * 4;
  const float invB = 1.0f / 65536.0f;

  float4 s = *(const float4*)(c.sum + col4);
  float4 q = *(const float4*)(c.sumsq + col4);
  float mu0 = s.x * invB, mu1 = s.y * invB, mu2 = s.z * invB, mu3 = s.w * invB;
  float rs0 = rsqrtf(q.x * invB - mu0 * mu0 + EPS_BN);
  float rs1 = rsqrtf(q.y * invB - mu1 * mu1 + EPS_BN);
  float rs2 = rsqrtf(q.z * invB - mu2 * mu2 + EPS_BN);
  float rs3 = rsqrtf(q.w * invB - mu3 * mu3 + EPS_BN);

  float4 g  = *(const float4*)(c.gamma + col4);
  float4 bt = *(const float4*)(c.beta + col4);
  float4 yv = *(const float4*)(c.y + e * 4);

  float4 o;
  o.x = g.x * (yv.x - mu0) * rs0 + bt.x;
  o.y = g.y * (yv.y - mu1) * rs1 + bt.y;
  o.z = g.z * (yv.z - mu2) * rs2 + bt.z;
  o.w = g.w * (yv.w - mu3) * rs3 + bt.w;
  if (c.noise) {
    float4 nz = *(const float4*)(c.noise + e * 4);
    o.x += NSTD * nz.x; o.y += NSTD * nz.y; o.z += NSTD * nz.z; o.w += NSTD * nz.w;
  }
  *(float4*)(c.out + e * 4) = o;
}

extern "C" void kernel_launch(void* const* d_in, const int* in_sizes, int n_in,
                              void* d_out, int out_size, void* d_ws, size_t ws_size,
                              hipStream_t stream) {
  const float* x1    = (const float*)d_in[0];
  const float* x2    = (const float*)d_in[1];
  const float* W1    = (const float*)d_in[2];
  const float* b1    = (const float*)d_in[3];
  const float* W2    = (const float*)d_in[4];
  const float* b2    = (const float*)d_in[5];
  const float* gamma = (const float*)d_in[6];
  const float* beta  = (const float*)d_in[7];
  const float* noise = (const float*)d_in[8];
  float* out = (float*)d_out;

  const size_t S = (size_t)BROWS * 128;
  float* o3 = out;
  float* o4 = out + S;
  float* o0 = out + 2 * S;
  float* o1 = out + 3 * S;
  float* o2 = out + 4 * S;

  float* stats = (float*)d_ws;                       // 5 x (sum[128], sumsq[128])
  short* wbuf  = (short*)((char*)d_ws + WOFF);       // split, fragment-major weights

  auto mkA = [&](int i, const float* pA, int ldA, const float* pB, int ldB, float* y) {
    NodeA n;
    n.inA = pA; n.inB = pB; n.ldA = ldA; n.ldB = ldB;
    n.w1t = wbuf + (size_t)i * WNODE;
    n.w2t = wbuf + (size_t)i * WNODE + 131072;
    n.b1 = b1 + (size_t)i * 256;
    n.b2 = b2 + (size_t)i * 128;
    n.y = y;
    n.sum = stats + i * 256;
    n.sumsq = stats + i * 256 + 128;
    return n;
  };
  auto mkC = [&](int i, float* y, const float* nz) {
    NodeC c;
    c.y = y; c.out = y;
    c.sum = stats + i * 256;
    c.sumsq = stats + i * 256 + 128;
    c.gamma = gamma + (size_t)i * 128;
    c.beta  = beta + (size_t)i * 128;
    c.noise = nz;
    return c;
  };

  // prep: zero stats, build split-bf16 tiled weights in ws
  zero_f32<<<dim3(5), dim3(256), 0, stream>>>(stats, 5 * 256);
  prep_weights<<<dim3(240), dim3(256), 0, stream>>>(W1, W2, wbuf);

  dim3 blkM(512), blkB(256);

  // nodes 0,1 (inputs x1,x2)
  NodeA a0 = mkA(0, x1, 256, x1 + 128, 256, o0);
  NodeA a1 = mkA(1, x2, 256, x2 + 128, 256, o1);
  mlp_node<<<dim3(BROWS / 64, 2), blkM, 0, stream>>>(a0, a1);
  NodeC c0 = mkC(0, o0, nullptr);
  NodeC c1 = mkC(1, o1, nullptr);
  bn_apply<<<dim3(S / 4 / 256, 2), blkB, 0, stream>>>(c0, c1);

  // node 2 (concat(o0,o1)) + noise[0]
  NodeA a2 = mkA(2, o0, 128, o1, 128, o2);
  mlp_node<<<dim3(BROWS / 64, 1), blkM, 0, stream>>>(a2, a2);
  NodeC c2 = mkC(2, o2, noise);
  bn_apply<<<dim3(S / 4 / 256, 1), blkB, 0, stream>>>(c2, c2);

  // nodes 3 (concat(o0,o2)), 4 (concat(o1,o2))
  NodeA a3 = mkA(3, o0, 128, o2, 128, o3);
  NodeA a4 = mkA(4, o1, 128, o2, 128, o4);
  mlp_node<<<dim3(BROWS / 64, 2), blkM, 0, stream>>>(a3, a4);
  NodeC c3 = mkC(3, o3, noise + S);
  NodeC c4 = mkC(4, o4, noise + 2 * S);
  bn_apply<<<dim3(S / 4 / 256, 2), blkB, 0, stream>>>(c3, c4);
}